// Round 1
// 661.245 us; speedup vs baseline: 1.0530x; 1.0530x over previous
//
#include <hip/hip_runtime.h>
#include <math.h>

#define I_DIM 256
#define O_DIM 2048
#define R_DIM 200000
#define K_SEL 2048
#define CAP   8192

// ---- workspace layout (offsets in u32 units) ----
#define WS_HIST   0         // u32[65536]
#define WS_META   65536     // u32[16]: [0]=B, [1]=tot, [2]=counter, [4]=norm f32
#define WS_CAND   65552     // u64[CAP] (16384 u32)
#define WS_IDX    81936     // i32[2048]
#define WS_SCALE  83984     // f32[2048]
#define WS_KEYS   86032     // u64[R] (400000 u32)
#define WS_RH     486032    // f32[I*O] (524288 u32)
#define WS_WXH    1010320   // f32[I*O] (524288 u32)
#define WS_X      1534608   // f32[I*O] (524288 u32)  x_topk in [k][j] layout

__device__ __forceinline__ unsigned sortable_key32(float f) {
    unsigned b = __float_as_uint(f);
    return (b & 0x80000000u) ? ~b : (b | 0x80000000u);
}
__device__ __forceinline__ float unsortable_key32(unsigned k) {
    unsigned b = (k & 0x80000000u) ? (k ^ 0x80000000u) : ~k;
    return __uint_as_float(b);
}

// K0: norm = fl32(sqrt(exact sum p^2)).
__global__ void norm_kernel(const float* __restrict__ p, float* __restrict__ norm_out) {
    if (threadIdx.x == 0) {
        double n = 0.0;
        for (int k = 0; k < I_DIM; k++) { double v = (double)p[k]; n += v * v; }
        norm_out[0] = (float)sqrt(n);
    }
}

// K1: bit-exact emulation of OpenBLAS sgemv_t (unchanged).
__global__ void __launch_bounds__(256) score_hist_kernel(
    const float* __restrict__ embs, const float* __restrict__ p,
    const float* __restrict__ mask, const float* __restrict__ normp,
    unsigned long long* __restrict__ keys, unsigned* __restrict__ hist) {
    __shared__ float sp[I_DIM];
    if (threadIdx.x < I_DIM) sp[threadIdx.x] = p[threadIdx.x];
    __syncthreads();
    const int r = blockIdx.x * 256 + threadIdx.x;
    if (r >= R_DIM) return;
    const float4* e4 = (const float4*)(embs + (size_t)r * I_DIM);
    const float4* p4 = (const float4*)sp;
    float L0=0.f,L1=0.f,L2=0.f,L3=0.f,L4=0.f,L5=0.f,L6=0.f,L7=0.f;
    #pragma unroll 4
    for (int i = 0; i < 32; i++) {          // 8 floats per iter (AVX2 YMM)
        float4 a = e4[2*i], b = e4[2*i+1];
        float4 qa = p4[2*i], qb = p4[2*i+1];
        L0 = fmaf(a.x, qa.x, L0);
        L1 = fmaf(a.y, qa.y, L1);
        L2 = fmaf(a.z, qa.z, L2);
        L3 = fmaf(a.w, qa.w, L3);
        L4 = fmaf(b.x, qb.x, L4);
        L5 = fmaf(b.y, qb.y, L5);
        L6 = fmaf(b.z, qb.z, L6);
        L7 = fmaf(b.w, qb.w, L7);
    }
    float t0 = L0 + L4, t1 = L1 + L5, t2 = L2 + L6, t3 = L3 + L7;
    float d = (t0 + t1) + (t2 + t3);
    float s = d / normp[0] + mask[r];
    unsigned k32 = sortable_key32(s);
    keys[r] = ((unsigned long long)k32 << 32) |
              (unsigned long long)(~(unsigned)r);   // lower idx wins ties
    atomicAdd(&hist[k32 >> 16], 1u);
}

// K2: find threshold bin B (unchanged).
__global__ void __launch_bounds__(1024) find_thresh_kernel(
    const unsigned* __restrict__ hist, unsigned* __restrict__ meta) {
    __shared__ unsigned T[1024];
    const int t = threadIdx.x;
    const int base = t * 64;
    unsigned s = 0;
    for (int b = 0; b < 64; b++) s += hist[base + b];
    T[t] = s;
    __syncthreads();
    if (t == 0) {
        unsigned run = 0;
        int chunk = 1023;
        while (chunk >= 0 && run + T[chunk] < K_SEL) { run += T[chunk]; chunk--; }
        unsigned B = 0, tot = run;
        if (chunk >= 0) {
            unsigned r2 = run;
            for (int b = 63; b >= 0; b--) {
                unsigned c = hist[chunk * 64 + b];
                if (r2 + c >= K_SEL) { B = (unsigned)(chunk * 64 + b); tot = r2 + c; break; }
                r2 += c;
            }
        }
        meta[0] = B;
        meta[1] = tot;
    }
}

// K3: compact keys with bin >= B (unchanged).
__global__ void __launch_bounds__(256) compact_kernel(
    const unsigned long long* __restrict__ keys,
    const unsigned* __restrict__ meta, unsigned* __restrict__ counter,
    unsigned long long* __restrict__ cand) {
    const unsigned B = meta[0];
    int i0 = blockIdx.x * blockDim.x + threadIdx.x;
    int stride = gridDim.x * blockDim.x;
    for (int r = i0; r < R_DIM; r += stride) {
        unsigned long long key = keys[r];
        if ((unsigned)(key >> 48) >= B) {
            unsigned slot = atomicAdd(counter, 1u);
            if (slot < CAP) cand[slot] = key;
        }
    }
}

// K4: exact global rank (unchanged).
__global__ void __launch_bounds__(256) rank_emit_kernel(
    const unsigned long long* __restrict__ cand,
    const unsigned* __restrict__ counter,
    int* __restrict__ sel_idx, float* __restrict__ sel_scale) {
    unsigned n = *counter;
    if (n > CAP) n = CAP;
    unsigned s = blockIdx.x * blockDim.x + threadIdx.x;
    if (s >= n) return;
    unsigned long long k1 = cand[s];
    unsigned rank = 0;
    for (unsigned q = 0; q < n; q++) rank += (cand[q] > k1) ? 1u : 0u;
    if (rank < K_SEL) {
        unsigned idxv = ~(unsigned)(k1 & 0xFFFFFFFFull);
        sel_idx[rank]   = (int)idxv;
        sel_scale[rank] = tanhf(unsortable_key32((unsigned)(k1 >> 32)));
    }
}

// K5: materialize X[k][j] = embs[sel_idx[j]][k] * scale[j].
// The stored value is the identical fp32 product the old gate kernel computed
// per-iteration (e[k]*sc rounds the same way) -> gate math stays bit-exact.
// Reads coalesced (each block streams one 1KB row); writes scattered but tiny
// (2MB total, absorbed by L2 write-back).
__global__ void __launch_bounds__(256) build_x_kernel(
    const float* __restrict__ embs, const int* __restrict__ sel_idx,
    const float* __restrict__ sel_scale, float* __restrict__ X) {
    const int j = blockIdx.x;
    const int row = sel_idx[j];
    const float sc = sel_scale[j];
    const int k = threadIdx.x;
    X[(size_t)k * O_DIM + j] = embs[(size_t)row * I_DIM + k] * sc;
}

// ==== GRU gates: register-tiled GEMMs ====
// Each thread owns one j column and TI=4 consecutive i rows (20 accumulators
// across the 5 gate products). X/history loads are coalesced 4B/lane; weight
// reads are wave-uniform (blockIdx.y-derived) -> scalar s_loads, no VALU cost.
// Per-accumulator FMA order is k-ascending, identical to the previous kernel.
#define TI 4

__global__ void __launch_bounds__(256) gate_ur_kernel(
    const float* __restrict__ X, const float* __restrict__ history,
    const float* __restrict__ Wu, const float* __restrict__ Uu,
    const float* __restrict__ bu,
    const float* __restrict__ Wr, const float* __restrict__ Ur,
    const float* __restrict__ br,
    const float* __restrict__ Wh,
    float* __restrict__ u_out, float* __restrict__ rh,
    float* __restrict__ wxh) {
    const int j  = blockIdx.x * 256 + threadIdx.x;
    const int i0 = blockIdx.y * TI;
    float uwx[TI] = {0.f,0.f,0.f,0.f};
    float uuh[TI] = {0.f,0.f,0.f,0.f};
    float rwx[TI] = {0.f,0.f,0.f,0.f};
    float ruh[TI] = {0.f,0.f,0.f,0.f};
    float hwx[TI] = {0.f,0.f,0.f,0.f};
    #pragma unroll 4
    for (int k = 0; k < I_DIM; k++) {
        const float xv = X[(size_t)k * O_DIM + j];
        const float hv = history[(size_t)k * O_DIM + j];
        #pragma unroll
        for (int ii = 0; ii < TI; ii++) {
            const size_t wo = (size_t)(i0 + ii) * I_DIM + k;
            uwx[ii] = fmaf(Wu[wo], xv, uwx[ii]);
            uuh[ii] = fmaf(Uu[wo], hv, uuh[ii]);
            rwx[ii] = fmaf(Wr[wo], xv, rwx[ii]);
            ruh[ii] = fmaf(Ur[wo], hv, ruh[ii]);
            hwx[ii] = fmaf(Wh[wo], xv, hwx[ii]);
        }
    }
    #pragma unroll
    for (int ii = 0; ii < TI; ii++) {
        const size_t o = (size_t)(i0 + ii) * O_DIM + j;
        float uz = uwx[ii] + uuh[ii] + bu[o];
        float rz = rwx[ii] + ruh[ii] + br[o];
        float ug = 1.f / (1.f + expf(-uz));
        float rg = 1.f / (1.f + expf(-rz));
        u_out[o] = ug;
        rh[o]    = rg * history[o];
        wxh[o]   = hwx[ii];
    }
}

__global__ void __launch_bounds__(256) gate_h_kernel(
    const float* __restrict__ history, const float* __restrict__ Uh,
    const float* __restrict__ bh,
    const float* __restrict__ u_out, const float* __restrict__ rh,
    const float* __restrict__ wxh, float* __restrict__ out) {
    const int j  = blockIdx.x * 256 + threadIdx.x;
    const int i0 = blockIdx.y * TI;
    float acc[TI] = {0.f,0.f,0.f,0.f};
    #pragma unroll 4
    for (int k = 0; k < I_DIM; k++) {
        const float rv = rh[(size_t)k * O_DIM + j];
        #pragma unroll
        for (int ii = 0; ii < TI; ii++)
            acc[ii] = fmaf(Uh[(size_t)(i0 + ii) * I_DIM + k], rv, acc[ii]);
    }
    #pragma unroll
    for (int ii = 0; ii < TI; ii++) {
        const size_t o = (size_t)(i0 + ii) * O_DIM + j;
        float hcap = tanhf(wxh[o] + acc[ii] + bh[o]);
        float ug = u_out[o];
        out[o] = (1.f - ug) * history[o] + ug * hcap;
    }
}

extern "C" void kernel_launch(void* const* d_in, const int* in_sizes, int n_in,
                              void* d_out, int out_size, void* d_ws, size_t ws_size,
                              hipStream_t stream) {
    const float* embs    = (const float*)d_in[0];
    const float* history = (const float*)d_in[1];
    const float* mask    = (const float*)d_in[2];
    const float* p       = (const float*)d_in[3];
    const float* Wu      = (const float*)d_in[4];
    const float* Uu      = (const float*)d_in[5];
    const float* bu      = (const float*)d_in[6];
    const float* Wr      = (const float*)d_in[7];
    const float* Ur      = (const float*)d_in[8];
    const float* br      = (const float*)d_in[9];
    const float* Wh      = (const float*)d_in[10];
    const float* Uh      = (const float*)d_in[11];
    const float* bh      = (const float*)d_in[12];
    float* out = (float*)d_out;

    unsigned* ws = (unsigned*)d_ws;
    unsigned* hist = ws + WS_HIST;
    unsigned* meta = ws + WS_META;
    unsigned long long* cand = (unsigned long long*)(ws + WS_CAND);
    int* sel_idx     = (int*)(ws + WS_IDX);
    float* sel_scale = (float*)(ws + WS_SCALE);
    unsigned long long* keys = (unsigned long long*)(ws + WS_KEYS);
    float* rh  = (float*)(ws + WS_RH);
    float* wxh = (float*)(ws + WS_WXH);
    float* X   = (float*)(ws + WS_X);
    float* normp = (float*)(meta + 4);

    hipMemsetAsync(ws, 0, (size_t)(WS_META + 16) * sizeof(unsigned), stream);

    hipLaunchKernelGGL(norm_kernel, dim3(1), dim3(64), 0, stream, p, normp);
    hipLaunchKernelGGL(score_hist_kernel, dim3((R_DIM + 255) / 256), dim3(256), 0, stream,
                       embs, p, mask, normp, keys, hist);
    hipLaunchKernelGGL(find_thresh_kernel, dim3(1), dim3(1024), 0, stream,
                       hist, meta);
    hipLaunchKernelGGL(compact_kernel, dim3(512), dim3(256), 0, stream,
                       keys, meta, meta + 2, cand);
    hipLaunchKernelGGL(rank_emit_kernel, dim3(CAP / 256), dim3(256), 0, stream,
                       cand, meta + 2, sel_idx, sel_scale);
    hipLaunchKernelGGL(build_x_kernel, dim3(K_SEL), dim3(256), 0, stream,
                       embs, sel_idx, sel_scale, X);
    hipLaunchKernelGGL(gate_ur_kernel, dim3(O_DIM / 256, I_DIM / TI), dim3(256), 0, stream,
                       X, history, Wu, Uu, bu, Wr, Ur, br, Wh,
                       sel_idx == 0 ? out : out /*u*/, rh, wxh);
    hipLaunchKernelGGL(gate_h_kernel, dim3(O_DIM / 256, I_DIM / TI), dim3(256), 0, stream,
                       history, Uh, bh, out /*u*/, rh, wxh, out);
}

// Round 2
// 567.545 us; speedup vs baseline: 1.2269x; 1.1651x over previous
//
#include <hip/hip_runtime.h>
#include <math.h>

#define I_DIM 256
#define O_DIM 2048
#define R_DIM 200000
#define K_SEL 2048
#define CAP   8192

// ---- workspace layout (offsets in u32 units) ----
#define WS_HIST   0         // u32[65536]
#define WS_META   65536     // u32[16]: [0]=B, [1]=tot, [2]=counter, [4]=norm f32
#define WS_CAND   65552     // u64[CAP] (16384 u32)
#define WS_IDX    81936     // i32[2048]
#define WS_SCALE  83984     // f32[2048]
#define WS_KEYS   86032     // u64[R] (400000 u32)
#define WS_RH     486032    // f32[I*O] (524288 u32)
#define WS_WXH    1010320   // f32[I*O] (524288 u32)
#define WS_X      1534608   // f32[I*O] (524288 u32)  x_topk in [k][j] layout

__device__ __forceinline__ unsigned sortable_key32(float f) {
    unsigned b = __float_as_uint(f);
    return (b & 0x80000000u) ? ~b : (b | 0x80000000u);
}
__device__ __forceinline__ float unsortable_key32(unsigned k) {
    unsigned b = (k & 0x80000000u) ? (k ^ 0x80000000u) : ~k;
    return __uint_as_float(b);
}

// K0: norm = fl32(sqrt(exact sum p^2)).
__global__ void norm_kernel(const float* __restrict__ p, float* __restrict__ norm_out) {
    if (threadIdx.x == 0) {
        double n = 0.0;
        for (int k = 0; k < I_DIM; k++) { double v = (double)p[k]; n += v * v; }
        norm_out[0] = (float)sqrt(n);
    }
}

// K1: bit-exact emulation of OpenBLAS sgemv_t (unchanged).
__global__ void __launch_bounds__(256) score_hist_kernel(
    const float* __restrict__ embs, const float* __restrict__ p,
    const float* __restrict__ mask, const float* __restrict__ normp,
    unsigned long long* __restrict__ keys, unsigned* __restrict__ hist) {
    __shared__ float sp[I_DIM];
    if (threadIdx.x < I_DIM) sp[threadIdx.x] = p[threadIdx.x];
    __syncthreads();
    const int r = blockIdx.x * 256 + threadIdx.x;
    if (r >= R_DIM) return;
    const float4* e4 = (const float4*)(embs + (size_t)r * I_DIM);
    const float4* p4 = (const float4*)sp;
    float L0=0.f,L1=0.f,L2=0.f,L3=0.f,L4=0.f,L5=0.f,L6=0.f,L7=0.f;
    #pragma unroll 4
    for (int i = 0; i < 32; i++) {          // 8 floats per iter (AVX2 YMM)
        float4 a = e4[2*i], b = e4[2*i+1];
        float4 qa = p4[2*i], qb = p4[2*i+1];
        L0 = fmaf(a.x, qa.x, L0);
        L1 = fmaf(a.y, qa.y, L1);
        L2 = fmaf(a.z, qa.z, L2);
        L3 = fmaf(a.w, qa.w, L3);
        L4 = fmaf(b.x, qb.x, L4);
        L5 = fmaf(b.y, qb.y, L5);
        L6 = fmaf(b.z, qb.z, L6);
        L7 = fmaf(b.w, qb.w, L7);
    }
    float t0 = L0 + L4, t1 = L1 + L5, t2 = L2 + L6, t3 = L3 + L7;
    float d = (t0 + t1) + (t2 + t3);
    float s = d / normp[0] + mask[r];
    unsigned k32 = sortable_key32(s);
    keys[r] = ((unsigned long long)k32 << 32) |
              (unsigned long long)(~(unsigned)r);   // lower idx wins ties
    atomicAdd(&hist[k32 >> 16], 1u);
}

// K2: find threshold bin B (unchanged).
__global__ void __launch_bounds__(1024) find_thresh_kernel(
    const unsigned* __restrict__ hist, unsigned* __restrict__ meta) {
    __shared__ unsigned T[1024];
    const int t = threadIdx.x;
    const int base = t * 64;
    unsigned s = 0;
    for (int b = 0; b < 64; b++) s += hist[base + b];
    T[t] = s;
    __syncthreads();
    if (t == 0) {
        unsigned run = 0;
        int chunk = 1023;
        while (chunk >= 0 && run + T[chunk] < K_SEL) { run += T[chunk]; chunk--; }
        unsigned B = 0, tot = run;
        if (chunk >= 0) {
            unsigned r2 = run;
            for (int b = 63; b >= 0; b--) {
                unsigned c = hist[chunk * 64 + b];
                if (r2 + c >= K_SEL) { B = (unsigned)(chunk * 64 + b); tot = r2 + c; break; }
                r2 += c;
            }
        }
        meta[0] = B;
        meta[1] = tot;
    }
}

// K3: compact keys with bin >= B (unchanged).
__global__ void __launch_bounds__(256) compact_kernel(
    const unsigned long long* __restrict__ keys,
    const unsigned* __restrict__ meta, unsigned* __restrict__ counter,
    unsigned long long* __restrict__ cand) {
    const unsigned B = meta[0];
    int i0 = blockIdx.x * blockDim.x + threadIdx.x;
    int stride = gridDim.x * blockDim.x;
    for (int r = i0; r < R_DIM; r += stride) {
        unsigned long long key = keys[r];
        if ((unsigned)(key >> 48) >= B) {
            unsigned slot = atomicAdd(counter, 1u);
            if (slot < CAP) cand[slot] = key;
        }
    }
}

// K4: exact global rank (unchanged).
__global__ void __launch_bounds__(256) rank_emit_kernel(
    const unsigned long long* __restrict__ cand,
    const unsigned* __restrict__ counter,
    int* __restrict__ sel_idx, float* __restrict__ sel_scale) {
    unsigned n = *counter;
    if (n > CAP) n = CAP;
    unsigned s = blockIdx.x * blockDim.x + threadIdx.x;
    if (s >= n) return;
    unsigned long long k1 = cand[s];
    unsigned rank = 0;
    for (unsigned q = 0; q < n; q++) rank += (cand[q] > k1) ? 1u : 0u;
    if (rank < K_SEL) {
        unsigned idxv = ~(unsigned)(k1 & 0xFFFFFFFFull);
        sel_idx[rank]   = (int)idxv;
        sel_scale[rank] = tanhf(unsortable_key32((unsigned)(k1 >> 32)));
    }
}

// K5: materialize X[k][j] = embs[sel_idx[j]][k] * scale[j] (unchanged).
__global__ void __launch_bounds__(256) build_x_kernel(
    const float* __restrict__ embs, const int* __restrict__ sel_idx,
    const float* __restrict__ sel_scale, float* __restrict__ X) {
    const int j = blockIdx.x;
    const int row = sel_idx[j];
    const float sc = sel_scale[j];
    const int k = threadIdx.x;
    X[(size_t)k * O_DIM + j] = embs[(size_t)row * I_DIM + k] * sc;
}

// ==== GRU gates v3: LDS weights + software-pipelined streaming loads ====
// Round-1 failure mode: compiler minimized to 24 VGPRs -> loads serialized
// (1 outstanding/wave, ~250cyc L2 latency each) -> VALUBusy 9%. Fix:
//   * weights staged once into LDS (20KB), read per k-group as broadcast
//     ds_read_b128 (uniform addr, conflict-free, fine-grained lgkm waits) --
//     removes the per-iteration SMEM lgkmcnt(0) drains.
//   * X/history loads software-pipelined in KG=8 groups with distinct named
//     prefetch registers -> 16 loads in flight per wave (need ~7 to cover
//     250cyc at 40cyc/k FMA rate).
// Per-accumulator FMA order stays k-ascending -> bit-identical to v2.
#define TI 4
#define KG 8

__global__ void __launch_bounds__(256) gate_ur_kernel(
    const float* __restrict__ X, const float* __restrict__ history,
    const float* __restrict__ Wu, const float* __restrict__ Uu,
    const float* __restrict__ bu,
    const float* __restrict__ Wr, const float* __restrict__ Ur,
    const float* __restrict__ br,
    const float* __restrict__ Wh,
    float* __restrict__ u_out, float* __restrict__ rh,
    float* __restrict__ wxh) {
    __shared__ float sw[5 * TI][I_DIM];   // 20 rows x 1KB = 20KB
    const int tid = threadIdx.x;
    const int j   = blockIdx.x * 256 + tid;
    const int i0  = blockIdx.y * TI;

    {   // stage weights: 20 coalesced rounds, one 1KB row each
        const float* mats[5] = {Wu, Uu, Wr, Ur, Wh};
        #pragma unroll
        for (int m = 0; m < 5; m++)
            #pragma unroll
            for (int ii = 0; ii < TI; ii++)
                sw[m * TI + ii][tid] = mats[m][(size_t)(i0 + ii) * I_DIM + tid];
    }
    __syncthreads();

    const float* Xp = X + j;
    const float* Hp = history + j;

    float acc[5][TI];
    #pragma unroll
    for (int m = 0; m < 5; m++)
        #pragma unroll
        for (int ii = 0; ii < TI; ii++) acc[m][ii] = 0.f;

    float xbuf[KG], hbuf[KG];
    #pragma unroll
    for (int t = 0; t < KG; t++) {
        xbuf[t] = Xp[(size_t)t * O_DIM];
        hbuf[t] = Hp[(size_t)t * O_DIM];
    }

    for (int k0 = 0; k0 < I_DIM; k0 += KG) {
        // prefetch next group unconditionally (dummy k=0 on last iter; the
        // values are rotated in but never consumed)
        const int kn = (k0 + KG < I_DIM) ? (k0 + KG) : 0;
        float xn[KG], hn[KG];
        #pragma unroll
        for (int t = 0; t < KG; t++) {
            xn[t] = Xp[(size_t)(kn + t) * O_DIM];
            hn[t] = Hp[(size_t)(kn + t) * O_DIM];
        }
        // compute current group: weights as float4 LDS reads (b128 broadcast)
        #pragma unroll
        for (int t4 = 0; t4 < KG / 4; t4++) {
            const int kb = k0 + t4 * 4;
            float4 w[5][TI];
            #pragma unroll
            for (int m = 0; m < 5; m++)
                #pragma unroll
                for (int ii = 0; ii < TI; ii++)
                    w[m][ii] = *(const float4*)&sw[m * TI + ii][kb];
            #pragma unroll
            for (int t = 0; t < 4; t++) {
                const float xv = xbuf[t4 * 4 + t];
                const float hv = hbuf[t4 * 4 + t];
                #pragma unroll
                for (int ii = 0; ii < TI; ii++) {
                    acc[0][ii] = fmaf(((const float*)&w[0][ii])[t], xv, acc[0][ii]);
                    acc[1][ii] = fmaf(((const float*)&w[1][ii])[t], hv, acc[1][ii]);
                    acc[2][ii] = fmaf(((const float*)&w[2][ii])[t], xv, acc[2][ii]);
                    acc[3][ii] = fmaf(((const float*)&w[3][ii])[t], hv, acc[3][ii]);
                    acc[4][ii] = fmaf(((const float*)&w[4][ii])[t], xv, acc[4][ii]);
                }
            }
        }
        #pragma unroll
        for (int t = 0; t < KG; t++) { xbuf[t] = xn[t]; hbuf[t] = hn[t]; }
    }

    #pragma unroll
    for (int ii = 0; ii < TI; ii++) {
        const size_t o = (size_t)(i0 + ii) * O_DIM + j;
        float uz = acc[0][ii] + acc[1][ii] + bu[o];
        float rz = acc[2][ii] + acc[3][ii] + br[o];
        float ug = 1.f / (1.f + expf(-uz));
        float rg = 1.f / (1.f + expf(-rz));
        u_out[o] = ug;
        rh[o]    = rg * history[o];
        wxh[o]   = acc[4][ii];
    }
}

// gate_h: 1 product, much more load-heavy per FMA -> deeper pipeline KG=16.
#define KGH 16

__global__ void __launch_bounds__(256) gate_h_kernel(
    const float* __restrict__ history, const float* __restrict__ Uh,
    const float* __restrict__ bh,
    const float* __restrict__ u_out, const float* __restrict__ rh,
    const float* __restrict__ wxh, float* __restrict__ out) {
    __shared__ float sw[TI][I_DIM];   // 4KB
    const int tid = threadIdx.x;
    const int j   = blockIdx.x * 256 + tid;
    const int i0  = blockIdx.y * TI;

    #pragma unroll
    for (int ii = 0; ii < TI; ii++)
        sw[ii][tid] = Uh[(size_t)(i0 + ii) * I_DIM + tid];
    __syncthreads();

    const float* Rp = rh + j;

    float acc[TI] = {0.f, 0.f, 0.f, 0.f};
    float rbuf[KGH];
    #pragma unroll
    for (int t = 0; t < KGH; t++) rbuf[t] = Rp[(size_t)t * O_DIM];

    for (int k0 = 0; k0 < I_DIM; k0 += KGH) {
        const int kn = (k0 + KGH < I_DIM) ? (k0 + KGH) : 0;
        float rn[KGH];
        #pragma unroll
        for (int t = 0; t < KGH; t++) rn[t] = Rp[(size_t)(kn + t) * O_DIM];
        #pragma unroll
        for (int t4 = 0; t4 < KGH / 4; t4++) {
            const int kb = k0 + t4 * 4;
            float4 w[TI];
            #pragma unroll
            for (int ii = 0; ii < TI; ii++)
                w[ii] = *(const float4*)&sw[ii][kb];
            #pragma unroll
            for (int t = 0; t < 4; t++) {
                const float rv = rbuf[t4 * 4 + t];
                #pragma unroll
                for (int ii = 0; ii < TI; ii++)
                    acc[ii] = fmaf(((const float*)&w[ii])[t], rv, acc[ii]);
            }
        }
        #pragma unroll
        for (int t = 0; t < KGH; t++) rbuf[t] = rn[t];
    }

    #pragma unroll
    for (int ii = 0; ii < TI; ii++) {
        const size_t o = (size_t)(i0 + ii) * O_DIM + j;
        float hcap = tanhf(wxh[o] + acc[ii] + bh[o]);
        float ug = u_out[o];
        out[o] = (1.f - ug) * history[o] + ug * hcap;
    }
}

extern "C" void kernel_launch(void* const* d_in, const int* in_sizes, int n_in,
                              void* d_out, int out_size, void* d_ws, size_t ws_size,
                              hipStream_t stream) {
    const float* embs    = (const float*)d_in[0];
    const float* history = (const float*)d_in[1];
    const float* mask    = (const float*)d_in[2];
    const float* p       = (const float*)d_in[3];
    const float* Wu      = (const float*)d_in[4];
    const float* Uu      = (const float*)d_in[5];
    const float* bu      = (const float*)d_in[6];
    const float* Wr      = (const float*)d_in[7];
    const float* Ur      = (const float*)d_in[8];
    const float* br      = (const float*)d_in[9];
    const float* Wh      = (const float*)d_in[10];
    const float* Uh      = (const float*)d_in[11];
    const float* bh      = (const float*)d_in[12];
    float* out = (float*)d_out;

    unsigned* ws = (unsigned*)d_ws;
    unsigned* hist = ws + WS_HIST;
    unsigned* meta = ws + WS_META;
    unsigned long long* cand = (unsigned long long*)(ws + WS_CAND);
    int* sel_idx     = (int*)(ws + WS_IDX);
    float* sel_scale = (float*)(ws + WS_SCALE);
    unsigned long long* keys = (unsigned long long*)(ws + WS_KEYS);
    float* rh  = (float*)(ws + WS_RH);
    float* wxh = (float*)(ws + WS_WXH);
    float* X   = (float*)(ws + WS_X);
    float* normp = (float*)(meta + 4);

    hipMemsetAsync(ws, 0, (size_t)(WS_META + 16) * sizeof(unsigned), stream);

    hipLaunchKernelGGL(norm_kernel, dim3(1), dim3(64), 0, stream, p, normp);
    hipLaunchKernelGGL(score_hist_kernel, dim3((R_DIM + 255) / 256), dim3(256), 0, stream,
                       embs, p, mask, normp, keys, hist);
    hipLaunchKernelGGL(find_thresh_kernel, dim3(1), dim3(1024), 0, stream,
                       hist, meta);
    hipLaunchKernelGGL(compact_kernel, dim3(512), dim3(256), 0, stream,
                       keys, meta, meta + 2, cand);
    hipLaunchKernelGGL(rank_emit_kernel, dim3(CAP / 256), dim3(256), 0, stream,
                       cand, meta + 2, sel_idx, sel_scale);
    hipLaunchKernelGGL(build_x_kernel, dim3(K_SEL), dim3(256), 0, stream,
                       embs, sel_idx, sel_scale, X);
    hipLaunchKernelGGL(gate_ur_kernel, dim3(O_DIM / 256, I_DIM / TI), dim3(256), 0, stream,
                       X, history, Wu, Uu, bu, Wr, Ur, br, Wh,
                       out /*u*/, rh, wxh);
    hipLaunchKernelGGL(gate_h_kernel, dim3(O_DIM / 256, I_DIM / TI), dim3(256), 0, stream,
                       history, Uh, bh, out /*u*/, rh, wxh, out);
}